// Round 11
// baseline (1008.177 us; speedup 1.0000x reference)
//
#include <hip/hip_runtime.h>

#define BATCH 4096
#define SEQ   2048
#define EMB   10
#define HID   50
#define VOCAB 14
#define TROW  2052     // token row stride bytes (u8): /4=513 ≡ 1 mod 32 -> conflict-free

using bf16x8 = __attribute__((ext_vector_type(8))) short;
using f32x4  = __attribute__((ext_vector_type(4))) float;
using f32x2  = __attribute__((ext_vector_type(2))) float;

__device__ __forceinline__ short f2bf(float f) {
  unsigned u = __builtin_bit_cast(unsigned, f);
  u = (u + 0x7FFFu + ((u >> 16) & 1u)) >> 16;   // round-to-nearest-even
  return (short)u;
}
__device__ __forceinline__ float fsigm(float x) {
  return __builtin_amdgcn_rcpf(1.0f + __builtin_amdgcn_exp2f(x * -1.44269504f));
}
// HW packed f32->bf16 (RNE) — 1 instr, bit-identical to f2bf pair.
__device__ __forceinline__ unsigned cvtpk(float lo, float hi) {
  unsigned r;
  asm("v_cvt_pk_bf16_f32 %0, %1, %2" : "=v"(r) : "v"(lo), "v"(hi));
  return r;
}

// Software exp2 on the VALU pipe (R20): 2^x = 2^k * 2^f, k=rndne(x),
// f in [-1/2,1/2]; 2^f by deg-4 Taylor in f (coeffs ln2^n/n!, truncation
// <= ln2^5/120 * 0.5^5 = 4.2e-5 rel — 100x below the bf16 h quantum).
// ldexp handles the full exponent range incl. saturation (k<<0 -> 0, same
// as HW exp2). Moves ~10 trans-pipe instrs/step off the critical SIMD onto
// cheap pk-VALU. Applied to FAT waves only.
__device__ __forceinline__ f32x2 exp2_pk(f32x2 x) {
  float k0 = __builtin_rintf(x[0]);
  float k1 = __builtin_rintf(x[1]);
  f32x2 f = x - f32x2{k0, k1};
  f32x2 p = f * 0.00961813f + 0.05550411f;   // c4, c3
  p = p * f + 0.24022651f;                   // c2
  p = p * f + 0.69314718f;                   // c1
  p = p * f + 1.0f;                          // c0
  return f32x2{__builtin_amdgcn_ldexpf(p[0], (int)k0),
               __builtin_amdgcn_ldexpf(p[1], (int)k1)};
}

// ---------------------------------------------------------------------------
// Pack A fragments (bf16, pre-scaled) for mfma_f32_16x16x32_bf16.
// 13 flat tiles. Tile tid, row m: q=m>>2 (dest quad), g=m&3 (gate).
//   tid<10  (fat pairs)  : jh = 2*((tid>>1)*4 + q) + (tid&1)   -> jh 0..39
//   tid>=10 (singles)    : jh = 40 + (tid-10)*4 + q            -> jh 40..51 (50,51 pad)
// Fat lanes thus own ADJACENT jh (2p, 2p+1) -> packed b32 h-write.
// i/f/o rows scaled by -log2e, g rows by -2log2e (fused-fraction epilogue).
//   k < 50 : W_hh[R][k]*scale ; k >= 50 : gxi[v=k-50][R]*scale,  R = g*50+jh
// ---------------------------------------------------------------------------
__global__ void prep_kernel(const float* __restrict__ emb,  const float* __restrict__ W_ih,
                            const float* __restrict__ W_hh, const float* __restrict__ b_ih,
                            const float* __restrict__ b_hh, short* __restrict__ Apack) {
  int idx = blockIdx.x * 256 + threadIdx.x;       // total 13*2*64*8 = 13312
  if (idx >= 13 * 2 * 64 * 8) return;
  int j    = idx & 7;
  int lane = (idx >> 3) & 63;
  int kf   = (idx >> 9) & 1;
  int tid  = idx >> 10;                            // tile 0..12
  int m    = lane & 15;
  int q    = m >> 2, g = m & 3;
  int jh   = (tid < 10) ? (2 * ((tid >> 1) * 4 + q) + (tid & 1))
                        : (40 + (tid - 10) * 4 + q);
  int k    = kf * 32 + (lane >> 4) * 8 + j;
  float v = 0.0f;
  if (jh < HID) {
    int R = g * HID + jh;
    float scale = (g == 2) ? -2.885390082f : -1.442695041f;
    if (k < HID) {
      v = W_hh[R * HID + k] * scale;
    } else {
      int vo = k - HID;                            // vocab id 0..13
      float s = b_ih[R] + b_hh[R];
      for (int e = 0; e < EMB; ++e) s += emb[vo * EMB + e] * W_ih[R * EMB + e];
      v = s * scale;
    }
  }
  Apack[idx] = f2bf(v);
}

// ---------------------------------------------------------------------------
// Main: 256 wgs x 512 threads (8 waves), one wg owns 16 batch rows.
// R20 = R16 (709 us, best) + software exp2 (exp2_pk) on FAT waves only.
// Lever ledger (single-lever tested): setprio@R16-placement +67 (kept);
// cvtpk +23 (kept); pk epilogue +12 (kept); window-widen -37, stagger -24,
// indep MFMA accs -60 (all reverted). Issue model: trans blocks issue
// ~12-16cy/wave64 (fit to VALUBusy 52%); critical SIMD1 = 24 trans ~380cy
// of ~500cy issue. exp2_pk trades each exp2-pair (32cy trans) for ~22cy
// pk-VALU -> SIMD1 -100cy if trans=16 (prediction: 670-690); +30cy if
// trans=8 (revert signal). Singles keep HW exp2 (their SIMDs have slack;
// shorter chain). Accuracy delta 4.2e-5 rel — negligible vs bf16 h.
// ---------------------------------------------------------------------------
__global__ __launch_bounds__(512, 1) void lstm_kernel(
    const int* __restrict__ tokens, const short* __restrict__ Apack,
    const float* __restrict__ W1, const float* __restrict__ b1,
    const float* __restrict__ W2, const float* __restrict__ b2,
    float* __restrict__ out) {
  __shared__ __align__(16) unsigned char toku8[16 * TROW];   // 32832 B
  __shared__ __align__(16) short hbuf[2][16 * 64];           // 4096 B, swizzled
  __shared__ float hfin[16 * 52];
  __shared__ float mlp_hid[16 * 52];

  const int tid  = threadIdx.x;
  const int lane = tid & 63;
  const int wv   = tid >> 6;
  const int b0   = blockIdx.x * 16;
  const int bB   = lane & 15;          // batch col (B-frag & C col)
  const int jj   = lane >> 4;          // quad

  // wave roles: fat mask {0,1,2,5,7} = 0xA7, singles {3,4,6} = 0x58
  const bool two = (0xA7 >> wv) & 1;
  const int  fr  = __builtin_popcount(0xA7 & ((1 << wv) - 1));  // fat rank
  const int  sr  = __builtin_popcount(0x58 & ((1 << wv) - 1));  // single rank
  const int  p   = fr * 4 + jj;                  // fat: jh pair (2p, 2p+1)
  const int  jhS = 40 + sr * 4 + jj;             // single: jh (50,51 = pad)
  const bool sval = !two && (jhS < HID);

  // persistent A fragments
  const int t0 = two ? (fr * 2) : (10 + sr);
  bf16x8 Af00 = *(const bf16x8*)(Apack + ((t0 * 2 + 0) * 64 + lane) * 8);
  bf16x8 Af01 = *(const bf16x8*)(Apack + ((t0 * 2 + 1) * 64 + lane) * 8);
  bf16x8 Af10 = {}, Af11 = {};
  if (two) {
    Af10 = *(const bf16x8*)(Apack + (((t0 + 1) * 2 + 0) * 64 + lane) * 8);
    Af11 = *(const bf16x8*)(Apack + (((t0 + 1) * 2 + 1) * 64 + lane) * 8);
  }

  // one-hot duty: waves 3,4 -> 56 lanes each (8 batch rows x 7 words)
  const bool ohact = (wv == 3 || wv == 4) && (lane < 56);
  const int ohr   = (wv - 3) * 8 + lane / 7;    // batch row 0..15
  const int ohsub = lane % 7;                    // word covering vocab 2w,2w+1
  const int ohoct = (ohsub < 3) ? 6 : 7;
  const int ohinn = (ohsub < 3) ? (4 + 4 * ohsub) : (4 * (ohsub - 3));
  const int ohb   = ohr * 128 + 16 * ((ohoct + ohr) & 7) + ohinn;
  const int ohv0  = 2 * ohsub, ohv1 = 2 * ohsub + 1;

  // ---- stage tokens (int32 -> u8) and zero hbuf[0]
  for (int i = tid; i < 16 * 512; i += 512) {          // 8192 int4-groups
    int row = i >> 9, c4 = i & 511;
    int4 tv = *(const int4*)&tokens[(b0 + row) * SEQ + 4 * c4];
    unsigned pk = (tv.x & 0xFF) | ((tv.y & 0xFF) << 8) |
                  ((tv.z & 0xFF) << 16) | ((tv.w & 0xFF) << 24);
    *(unsigned*)&toku8[row * TROW + 4 * c4] = pk;
  }
  for (int i = tid; i < 1024; i += 512) hbuf[0][i] = 0;
  __syncthreads();

  // loop-invariant LDS byte offsets (XOR-swizzled 128 B rows)
  char* hb = (char*)hbuf;
  const int rb0   = bB * 128 + 16 * ((jj + bB) & 7);          // B octet jj
  const int rb1   = bB * 128 + 16 * (((jj + 4) + bB) & 7);    // B octet jj+4
  const int hwb32 = bB * 128 + 16 * (((p >> 2) + bB) & 7) + ((4 * p) & 15);
  const int hwb16 = bB * 128 + 16 * (((jhS >> 3) + bB) & 7) + 2 * (jhS & 7);
  const unsigned char* myrow = &toku8[bB * TROW];    // keep-mask tokens
  const unsigned char* ohtok = &toku8[ohr * TROW];   // one-hot tokens

  // one-hot for t=0
  if (ohact) {
    int tk = ohtok[0];
    unsigned wb = ((tk == ohv0) ? 0x3F80u : 0u) | ((tk == ohv1) ? 0x3F800000u : 0u);
    *(unsigned*)(hb + ohb) = wb;
  }

  float c0 = 0.f, h0 = 0.f, c1 = 0.f, h1 = 0.f;
  unsigned mp = 0;

  for (int t = 0; t < SEQ; t += 16) {
#pragma unroll
    for (int u = 0; u < 16; ++u) {
      const int T  = t + u;
      const int PB = (u & 1) * 2048, PN = PB ^ 2048;
      __syncthreads();   // hbuf[PB] ready; LDS-only -> lgkmcnt drain

      bf16x8 Bf0 = *(const bf16x8*)(hb + PB + rb0);
      bf16x8 Bf1 = *(const bf16x8*)(hb + PB + rb1);
      if ((u & 3) == 0) mp = *(const unsigned*)(myrow + T);   // tokens T..T+3

      const bool keep = (((mp >> (8 * (u & 3))) & 0xFF) != 0);

      if (two) {
        // ---- fat waves: prioritized MFMA + epilogue (R16 placement, prio1)
        __builtin_amdgcn_s_setprio(1);
        f32x4 acc0 = {0.f, 0.f, 0.f, 0.f};
        acc0 = __builtin_amdgcn_mfma_f32_16x16x32_bf16(Af00, Bf0, acc0, 0, 0, 0);
        acc0 = __builtin_amdgcn_mfma_f32_16x16x32_bf16(Af01, Bf1, acc0, 0, 0, 0);
        f32x4 acc1 = {0.f, 0.f, 0.f, 0.f};
        acc1 = __builtin_amdgcn_mfma_f32_16x16x32_bf16(Af10, Bf0, acc1, 0, 0, 0);
        acc1 = __builtin_amdgcn_mfma_f32_16x16x32_bf16(Af11, Bf1, acc1, 0, 0, 0);

        // paired fused-fraction cells, packed-f32 form; exp2 on VALU pipe
        f32x2 eA = exp2_pk(f32x2{acc0[0], acc1[0]});
        f32x2 eB = exp2_pk(f32x2{acc0[1], acc1[1]});
        f32x2 eC = exp2_pk(f32x2{acc0[2], acc1[2]});
        f32x2 eG = exp2_pk(f32x2{acc0[3], acc1[3]});
        const f32x2 one2 = {1.f, 1.f};
        f32x2 bb = one2 + eB;
        f32x2 cc = one2 + eC;
        f32x2 gg = one2 + eG;
        f32x2 P  = eA * cc + cc;          // (1+eA)*(1+eC)
        f32x2 t1 = bb - eC * bb;          // b1*(1-eC)
        f32x2 cs = {c0, c1};
        f32x2 num = cs * P + t1;
        f32x2 den = P * bb;
        float r   = __builtin_amdgcn_rcpf(den[0] * den[1]);
        float cn0 = num[0] * (den[1] * r);
        float cn1 = num[1] * (den[0] * r);
        float cl0 = fminf(cn0 * -2.885390082f, 40.0f);
        float cl1 = fminf(cn1 * -2.885390082f, 40.0f);
        f32x2 H = exp2_pk(f32x2{cl0, cl1});
        f32x2 hd = gg * H + gg;           // g1*(1+H)
        float rh = __builtin_amdgcn_rcpf(hd[0] * hd[1]);
        f32x2 hnum = one2 - H;
        float hn0 = hnum[0] * (hd[1] * rh);
        float hn1 = hnum[1] * (hd[0] * rh);
        c0 = keep ? cn0 : c0;  h0 = keep ? hn0 : h0;
        c1 = keep ? cn1 : c1;  h1 = keep ? hn1 : h1;
        *(unsigned*)(hb + PN + hwb32) = cvtpk(h0, h1);
        __builtin_amdgcn_s_setprio(0);
      } else {
        // ---- singles: one-hot for T+1 FIRST (token-only dep, fills ds_read
        // latency), then MFMA + short epilogue (HW exp2 — SIMD has slack)
        if (ohact && T + 1 < SEQ) {
          int tk = ohtok[T + 1];
          unsigned wb = ((tk == ohv0) ? 0x3F80u : 0u) |
                        ((tk == ohv1) ? 0x3F800000u : 0u);
          *(unsigned*)(hb + PN + ohb) = wb;
        }

        f32x4 acc0 = {0.f, 0.f, 0.f, 0.f};
        acc0 = __builtin_amdgcn_mfma_f32_16x16x32_bf16(Af00, Bf0, acc0, 0, 0, 0);
        acc0 = __builtin_amdgcn_mfma_f32_16x16x32_bf16(Af01, Bf1, acc0, 0, 0, 0);

        // single fused-fraction cell: 5 exp2 + 2 rcp, fma-folded
        float eA = __builtin_amdgcn_exp2f(acc0[0]);
        float eB = __builtin_amdgcn_exp2f(acc0[1]);
        float eC = __builtin_amdgcn_exp2f(acc0[2]);
        float eG = __builtin_amdgcn_exp2f(acc0[3]);
        float bb1 = 1.f + eB, cc1 = 1.f + eC, g1 = 1.f + eG;
        float P   = __builtin_fmaf(eA, cc1, cc1);     // (1+eA)*(1+eC)
        float t1  = __builtin_fmaf(-eC, bb1, bb1);
        float num = __builtin_fmaf(c0, P, t1);
        float den = P * bb1;
        float cn  = num * __builtin_amdgcn_rcpf(den);
        float cl  = fminf(cn * -2.885390082f, 40.0f);
        float eH  = __builtin_amdgcn_exp2f(cl);
        float hd  = __builtin_fmaf(g1, eH, g1);       // g1*(1+H)
        float hn  = (1.f - eH) * __builtin_amdgcn_rcpf(hd);
        c0 = keep ? cn : c0;
        h0 = keep ? hn : h0;
        if (sval) *(short*)(hb + PN + hwb16) = (short)cvtpk(h0, h0);
      }
    }
  }

  // ---- final h -> MLP -> sigmoid
  if (two) {
    hfin[bB * 52 + 2 * p]     = h0;
    hfin[bB * 52 + 2 * p + 1] = h1;
  } else if (sval) {
    hfin[bB * 52 + jhS] = h0;
  }
  __syncthreads();
  for (int idx = tid; idx < 16 * 64; idx += 512) {
    int b = idx >> 6, m = idx & 63;
    if (m < HID) {
      float s = b1[m];
      for (int j2 = 0; j2 < HID; ++j2) s += hfin[b * 52 + j2] * W1[m * HID + j2];
      mlp_hid[b * 52 + m] = s;
    }
  }
  __syncthreads();
  if (tid < 16) {
    float s = b2[0];
    for (int m2 = 0; m2 < HID; ++m2) s += mlp_hid[tid * 52 + m2] * W2[m2];
    out[b0 + tid] = fsigm(s);
  }
}

extern "C" void kernel_launch(void* const* d_in, const int* in_sizes, int n_in,
                              void* d_out, int out_size, void* d_ws, size_t ws_size,
                              hipStream_t stream) {
  const int*   tokens = (const int*)  d_in[0];
  const float* emb    = (const float*)d_in[1];
  const float* W_ih   = (const float*)d_in[2];
  const float* W_hh   = (const float*)d_in[3];
  const float* b_ih   = (const float*)d_in[4];
  const float* b_hh   = (const float*)d_in[5];
  const float* W1     = (const float*)d_in[6];
  const float* b1     = (const float*)d_in[7];
  const float* W2     = (const float*)d_in[8];
  const float* b2     = (const float*)d_in[9];
  float* outp  = (float*)d_out;
  short* Apack = (short*)d_ws;                 // 13312 bf16 = 26.6 KB

  hipLaunchKernelGGL(prep_kernel, dim3(52), dim3(256), 0, stream,
                     emb, W_ih, W_hh, b_ih, b_hh, Apack);
  hipLaunchKernelGGL(lstm_kernel, dim3(BATCH / 16), dim3(512), 0, stream,
                     tokens, Apack, W1, b1, W2, b2, outp);
}

// Round 12
// 700.222 us; speedup vs baseline: 1.4398x; 1.4398x over previous
//
#include <hip/hip_runtime.h>

#define BATCH 4096
#define SEQ   2048
#define EMB   10
#define HID   50
#define VOCAB 14
#define TROW  2052     // token row stride bytes (u8): /4=513 ≡ 1 mod 32 -> conflict-free

using bf16x8 = __attribute__((ext_vector_type(8))) short;
using f32x4  = __attribute__((ext_vector_type(4))) float;
using f32x2  = __attribute__((ext_vector_type(2))) float;

__device__ __forceinline__ short f2bf(float f) {
  unsigned u = __builtin_bit_cast(unsigned, f);
  u = (u + 0x7FFFu + ((u >> 16) & 1u)) >> 16;   // round-to-nearest-even
  return (short)u;
}
__device__ __forceinline__ float fsigm(float x) {
  return __builtin_amdgcn_rcpf(1.0f + __builtin_amdgcn_exp2f(x * -1.44269504f));
}
// HW packed f32->bf16 (RNE) — 1 instr, bit-identical to f2bf pair.
__device__ __forceinline__ unsigned cvtpk(float lo, float hi) {
  unsigned r;
  asm("v_cvt_pk_bf16_f32 %0, %1, %2" : "=v"(r) : "v"(lo), "v"(hi));
  return r;
}

// ---------------------------------------------------------------------------
// Pack A fragments (bf16, pre-scaled) for mfma_f32_16x16x32_bf16.
// 13 flat tiles. Tile tid, row m: q=m>>2 (dest quad), g=m&3 (gate).
//   tid<10  (fat pairs)  : jh = 2*((tid>>1)*4 + q) + (tid&1)   -> jh 0..39
//   tid>=10 (singles)    : jh = 40 + (tid-10)*4 + q            -> jh 40..51 (50,51 pad)
// Fat lanes thus own ADJACENT jh (2p, 2p+1) -> packed b32 h-write.
// i/f/o rows scaled by -log2e, g rows by -2log2e (fused-fraction epilogue).
//   k < 50 : W_hh[R][k]*scale ; k >= 50 : gxi[v=k-50][R]*scale,  R = g*50+jh
// ---------------------------------------------------------------------------
__global__ void prep_kernel(const float* __restrict__ emb,  const float* __restrict__ W_ih,
                            const float* __restrict__ W_hh, const float* __restrict__ b_ih,
                            const float* __restrict__ b_hh, short* __restrict__ Apack) {
  int idx = blockIdx.x * 256 + threadIdx.x;       // total 13*2*64*8 = 13312
  if (idx >= 13 * 2 * 64 * 8) return;
  int j    = idx & 7;
  int lane = (idx >> 3) & 63;
  int kf   = (idx >> 9) & 1;
  int tid  = idx >> 10;                            // tile 0..12
  int m    = lane & 15;
  int q    = m >> 2, g = m & 3;
  int jh   = (tid < 10) ? (2 * ((tid >> 1) * 4 + q) + (tid & 1))
                        : (40 + (tid - 10) * 4 + q);
  int k    = kf * 32 + (lane >> 4) * 8 + j;
  float v = 0.0f;
  if (jh < HID) {
    int R = g * HID + jh;
    float scale = (g == 2) ? -2.885390082f : -1.442695041f;
    if (k < HID) {
      v = W_hh[R * HID + k] * scale;
    } else {
      int vo = k - HID;                            // vocab id 0..13
      float s = b_ih[R] + b_hh[R];
      for (int e = 0; e < EMB; ++e) s += emb[vo * EMB + e] * W_ih[R * EMB + e];
      v = s * scale;
    }
  }
  Apack[idx] = f2bf(v);
}

// ---------------------------------------------------------------------------
// Main: 256 wgs x 512 threads (8 waves), one wg owns 16 batch rows.
// R21 = R16 (709 us, best) + deeper pk-ification of the FAT epilogue only.
// R20 post-mortem: software exp2 -300us -> HW trans is CHEAP (issue ~2-4cy,
// decoupled pipe); the "trans 12-16cy" fit was wrong. VALUBusy ~52% is real
// VALU. Period 830 = chain (~450) + SIMD1's serialized fat-epilogue VALU
// (2 x ~100cy) + skew. VALU-count cuts on fats paid ~1:1 (cvtpk -23us,
// pk -12us). This round: state carried as f32x2 (no repack movs), cn/cl/hn
// computed as pk ops with op_sel swizzles: ~-7 VALU/fat wave.
//   cn = num * (swz(den)*r); clv = cn*k (pk); hn = (1-H) * (swz(hd)*rh).
// Same products, f32 reassociation only — far below bf16 tolerance.
// ---------------------------------------------------------------------------
__global__ __launch_bounds__(512, 1) void lstm_kernel(
    const int* __restrict__ tokens, const short* __restrict__ Apack,
    const float* __restrict__ W1, const float* __restrict__ b1,
    const float* __restrict__ W2, const float* __restrict__ b2,
    float* __restrict__ out) {
  __shared__ __align__(16) unsigned char toku8[16 * TROW];   // 32832 B
  __shared__ __align__(16) short hbuf[2][16 * 64];           // 4096 B, swizzled
  __shared__ float hfin[16 * 52];
  __shared__ float mlp_hid[16 * 52];

  const int tid  = threadIdx.x;
  const int lane = tid & 63;
  const int wv   = tid >> 6;
  const int b0   = blockIdx.x * 16;
  const int bB   = lane & 15;          // batch col (B-frag & C col)
  const int jj   = lane >> 4;          // quad

  // wave roles: fat mask {0,1,2,5,7} = 0xA7, singles {3,4,6} = 0x58
  const bool two = (0xA7 >> wv) & 1;
  const int  fr  = __builtin_popcount(0xA7 & ((1 << wv) - 1));  // fat rank
  const int  sr  = __builtin_popcount(0x58 & ((1 << wv) - 1));  // single rank
  const int  p   = fr * 4 + jj;                  // fat: jh pair (2p, 2p+1)
  const int  jhS = 40 + sr * 4 + jj;             // single: jh (50,51 = pad)
  const bool sval = !two && (jhS < HID);

  // persistent A fragments
  const int t0 = two ? (fr * 2) : (10 + sr);
  bf16x8 Af00 = *(const bf16x8*)(Apack + ((t0 * 2 + 0) * 64 + lane) * 8);
  bf16x8 Af01 = *(const bf16x8*)(Apack + ((t0 * 2 + 1) * 64 + lane) * 8);
  bf16x8 Af10 = {}, Af11 = {};
  if (two) {
    Af10 = *(const bf16x8*)(Apack + (((t0 + 1) * 2 + 0) * 64 + lane) * 8);
    Af11 = *(const bf16x8*)(Apack + (((t0 + 1) * 2 + 1) * 64 + lane) * 8);
  }

  // one-hot duty: waves 3,4 -> 56 lanes each (8 batch rows x 7 words)
  const bool ohact = (wv == 3 || wv == 4) && (lane < 56);
  const int ohr   = (wv - 3) * 8 + lane / 7;    // batch row 0..15
  const int ohsub = lane % 7;                    // word covering vocab 2w,2w+1
  const int ohoct = (ohsub < 3) ? 6 : 7;
  const int ohinn = (ohsub < 3) ? (4 + 4 * ohsub) : (4 * (ohsub - 3));
  const int ohb   = ohr * 128 + 16 * ((ohoct + ohr) & 7) + ohinn;
  const int ohv0  = 2 * ohsub, ohv1 = 2 * ohsub + 1;

  // ---- stage tokens (int32 -> u8) and zero hbuf[0]
  for (int i = tid; i < 16 * 512; i += 512) {          // 8192 int4-groups
    int row = i >> 9, c4 = i & 511;
    int4 tv = *(const int4*)&tokens[(b0 + row) * SEQ + 4 * c4];
    unsigned pk = (tv.x & 0xFF) | ((tv.y & 0xFF) << 8) |
                  ((tv.z & 0xFF) << 16) | ((tv.w & 0xFF) << 24);
    *(unsigned*)&toku8[row * TROW + 4 * c4] = pk;
  }
  for (int i = tid; i < 1024; i += 512) hbuf[0][i] = 0;
  __syncthreads();

  // loop-invariant LDS byte offsets (XOR-swizzled 128 B rows)
  char* hb = (char*)hbuf;
  const int rb0   = bB * 128 + 16 * ((jj + bB) & 7);          // B octet jj
  const int rb1   = bB * 128 + 16 * (((jj + 4) + bB) & 7);    // B octet jj+4
  const int hwb32 = bB * 128 + 16 * (((p >> 2) + bB) & 7) + ((4 * p) & 15);
  const int hwb16 = bB * 128 + 16 * (((jhS >> 3) + bB) & 7) + 2 * (jhS & 7);
  const unsigned char* myrow = &toku8[bB * TROW];    // keep-mask tokens
  const unsigned char* ohtok = &toku8[ohr * TROW];   // one-hot tokens

  // one-hot for t=0
  if (ohact) {
    int tk = ohtok[0];
    unsigned wb = ((tk == ohv0) ? 0x3F80u : 0u) | ((tk == ohv1) ? 0x3F800000u : 0u);
    *(unsigned*)(hb + ohb) = wb;
  }

  f32x2 c01 = {0.f, 0.f}, h01 = {0.f, 0.f};   // fat: 2 cells; single uses [0]
  unsigned mp = 0;

  for (int t = 0; t < SEQ; t += 16) {
#pragma unroll
    for (int u = 0; u < 16; ++u) {
      const int T  = t + u;
      const int PB = (u & 1) * 2048, PN = PB ^ 2048;
      __syncthreads();   // hbuf[PB] ready; LDS-only -> lgkmcnt drain

      bf16x8 Bf0 = *(const bf16x8*)(hb + PB + rb0);
      bf16x8 Bf1 = *(const bf16x8*)(hb + PB + rb1);
      if ((u & 3) == 0) mp = *(const unsigned*)(myrow + T);   // tokens T..T+3

      const bool keep = (((mp >> (8 * (u & 3))) & 0xFF) != 0);

      if (two) {
        // ---- fat waves: prioritized MFMA + epilogue (R16 placement, prio1)
        __builtin_amdgcn_s_setprio(1);
        f32x4 acc0 = {0.f, 0.f, 0.f, 0.f};
        acc0 = __builtin_amdgcn_mfma_f32_16x16x32_bf16(Af00, Bf0, acc0, 0, 0, 0);
        acc0 = __builtin_amdgcn_mfma_f32_16x16x32_bf16(Af01, Bf1, acc0, 0, 0, 0);
        f32x4 acc1 = {0.f, 0.f, 0.f, 0.f};
        acc1 = __builtin_amdgcn_mfma_f32_16x16x32_bf16(Af10, Bf0, acc1, 0, 0, 0);
        acc1 = __builtin_amdgcn_mfma_f32_16x16x32_bf16(Af11, Bf1, acc1, 0, 0, 0);

        // paired fused-fraction cells, fully packed-f32 form
        f32x2 eA = {__builtin_amdgcn_exp2f(acc0[0]), __builtin_amdgcn_exp2f(acc1[0])};
        f32x2 eB = {__builtin_amdgcn_exp2f(acc0[1]), __builtin_amdgcn_exp2f(acc1[1])};
        f32x2 eC = {__builtin_amdgcn_exp2f(acc0[2]), __builtin_amdgcn_exp2f(acc1[2])};
        f32x2 eG = {__builtin_amdgcn_exp2f(acc0[3]), __builtin_amdgcn_exp2f(acc1[3])};
        const f32x2 one2 = {1.f, 1.f};
        f32x2 bb = one2 + eB;
        f32x2 cc = one2 + eC;
        f32x2 gg = one2 + eG;
        f32x2 P  = eA * cc + cc;          // (1+eA)*(1+eC)
        f32x2 t1 = bb - eC * bb;          // b1*(1-eC)
        f32x2 num = c01 * P + t1;
        f32x2 den = P * bb;
        float r   = __builtin_amdgcn_rcpf(den[0] * den[1]);
        f32x2 cw  = f32x2{den[1], den[0]} * r;   // pk-mul w/ op_sel swizzle
        f32x2 cn  = num * cw;
        f32x2 clv = cn * -2.885390082f;          // pk-mul
        float cl0 = fminf(clv[0], 40.0f);
        float cl1 = fminf(clv[1], 40.0f);
        f32x2 H = {__builtin_amdgcn_exp2f(cl0), __builtin_amdgcn_exp2f(cl1)};
        f32x2 hd = gg * H + gg;           // g1*(1+H)
        float rh = __builtin_amdgcn_rcpf(hd[0] * hd[1]);
        f32x2 hw = f32x2{hd[1], hd[0]} * rh;     // pk-mul w/ op_sel swizzle
        f32x2 hn = (one2 - H) * hw;
        c01[0] = keep ? cn[0] : c01[0];  h01[0] = keep ? hn[0] : h01[0];
        c01[1] = keep ? cn[1] : c01[1];  h01[1] = keep ? hn[1] : h01[1];
        *(unsigned*)(hb + PN + hwb32) = cvtpk(h01[0], h01[1]);
        __builtin_amdgcn_s_setprio(0);
      } else {
        // ---- singles: one-hot for T+1 FIRST (token-only dep, fills ds_read
        // latency), then MFMA + short epilogue (unchanged from R16)
        if (ohact && T + 1 < SEQ) {
          int tk = ohtok[T + 1];
          unsigned wb = ((tk == ohv0) ? 0x3F80u : 0u) |
                        ((tk == ohv1) ? 0x3F800000u : 0u);
          *(unsigned*)(hb + PN + ohb) = wb;
        }

        f32x4 acc0 = {0.f, 0.f, 0.f, 0.f};
        acc0 = __builtin_amdgcn_mfma_f32_16x16x32_bf16(Af00, Bf0, acc0, 0, 0, 0);
        acc0 = __builtin_amdgcn_mfma_f32_16x16x32_bf16(Af01, Bf1, acc0, 0, 0, 0);

        // single fused-fraction cell: 5 exp2 + 2 rcp, fma-folded
        float eA = __builtin_amdgcn_exp2f(acc0[0]);
        float eB = __builtin_amdgcn_exp2f(acc0[1]);
        float eC = __builtin_amdgcn_exp2f(acc0[2]);
        float eG = __builtin_amdgcn_exp2f(acc0[3]);
        float bb1 = 1.f + eB, cc1 = 1.f + eC, g1 = 1.f + eG;
        float P   = __builtin_fmaf(eA, cc1, cc1);     // (1+eA)*(1+eC)
        float t1  = __builtin_fmaf(-eC, bb1, bb1);
        float num = __builtin_fmaf(c01[0], P, t1);
        float den = P * bb1;
        float cn  = num * __builtin_amdgcn_rcpf(den);
        float cl  = fminf(cn * -2.885390082f, 40.0f);
        float eH  = __builtin_amdgcn_exp2f(cl);
        float hd  = __builtin_fmaf(g1, eH, g1);       // g1*(1+H)
        float hn  = (1.f - eH) * __builtin_amdgcn_rcpf(hd);
        c01[0] = keep ? cn : c01[0];
        h01[0] = keep ? hn : h01[0];
        if (sval) *(short*)(hb + PN + hwb16) = (short)cvtpk(h01[0], h01[0]);
      }
    }
  }

  // ---- final h -> MLP -> sigmoid
  if (two) {
    hfin[bB * 52 + 2 * p]     = h01[0];
    hfin[bB * 52 + 2 * p + 1] = h01[1];
  } else if (sval) {
    hfin[bB * 52 + jhS] = h01[0];
  }
  __syncthreads();
  for (int idx = tid; idx < 16 * 64; idx += 512) {
    int b = idx >> 6, m = idx & 63;
    if (m < HID) {
      float s = b1[m];
      for (int j2 = 0; j2 < HID; ++j2) s += hfin[b * 52 + j2] * W1[m * HID + j2];
      mlp_hid[b * 52 + m] = s;
    }
  }
  __syncthreads();
  if (tid < 16) {
    float s = b2[0];
    for (int m2 = 0; m2 < HID; ++m2) s += mlp_hid[tid * 52 + m2] * W2[m2];
    out[b0 + tid] = fsigm(s);
  }
}

extern "C" void kernel_launch(void* const* d_in, const int* in_sizes, int n_in,
                              void* d_out, int out_size, void* d_ws, size_t ws_size,
                              hipStream_t stream) {
  const int*   tokens = (const int*)  d_in[0];
  const float* emb    = (const float*)d_in[1];
  const float* W_ih   = (const float*)d_in[2];
  const float* W_hh   = (const float*)d_in[3];
  const float* b_ih   = (const float*)d_in[4];
  const float* b_hh   = (const float*)d_in[5];
  const float* W1     = (const float*)d_in[6];
  const float* b1     = (const float*)d_in[7];
  const float* W2     = (const float*)d_in[8];
  const float* b2     = (const float*)d_in[9];
  float* outp  = (float*)d_out;
  short* Apack = (short*)d_ws;                 // 13312 bf16 = 26.6 KB

  hipLaunchKernelGGL(prep_kernel, dim3(52), dim3(256), 0, stream,
                     emb, W_ih, W_hh, b_ih, b_hh, Apack);
  hipLaunchKernelGGL(lstm_kernel, dim3(BATCH / 16), dim3(512), 0, stream,
                     tokens, Apack, W1, b1, W2, b2, outp);
}

// Round 14
// 699.192 us; speedup vs baseline: 1.4419x; 1.0015x over previous
//
#include <hip/hip_runtime.h>

#define BATCH 4096
#define SEQ   2048
#define EMB   10
#define HID   50
#define VOCAB 14
#define TROW  2052     // token row stride bytes (u8): /4=513 ≡ 1 mod 32 -> conflict-free

using bf16x8 = __attribute__((ext_vector_type(8))) short;
using f32x4  = __attribute__((ext_vector_type(4))) float;
using f32x2  = __attribute__((ext_vector_type(2))) float;

__device__ __forceinline__ short f2bf(float f) {
  unsigned u = __builtin_bit_cast(unsigned, f);
  u = (u + 0x7FFFu + ((u >> 16) & 1u)) >> 16;   // round-to-nearest-even
  return (short)u;
}
__device__ __forceinline__ float fsigm(float x) {
  return __builtin_amdgcn_rcpf(1.0f + __builtin_amdgcn_exp2f(x * -1.44269504f));
}
// HW packed f32->bf16 (RNE) — 1 instr, bit-identical to f2bf pair.
__device__ __forceinline__ unsigned cvtpk(float lo, float hi) {
  unsigned r;
  asm("v_cvt_pk_bf16_f32 %0, %1, %2" : "=v"(r) : "v"(lo), "v"(hi));
  return r;
}

// ---------------------------------------------------------------------------
// Pack A fragments (bf16, pre-scaled) for mfma_f32_16x16x32_bf16.
// 13 flat tiles. Tile tid, row m: q=m>>2 (dest quad), g=m&3 (gate).
//   tid<10  (fat pairs)  : jh = 2*((tid>>1)*4 + q) + (tid&1)   -> jh 0..39
//   tid>=10 (singles)    : jh = 40 + (tid-10)*4 + q            -> jh 40..51 (50,51 pad)
// Fat lanes thus own ADJACENT jh (2p, 2p+1) -> packed b32 h-write.
// i/f/o rows scaled by -log2e, g rows by -2log2e (fused-fraction epilogue).
//   k < 50 : W_hh[R][k]*scale ; k >= 50 : gxi[v=k-50][R]*scale,  R = g*50+jh
// ---------------------------------------------------------------------------
__global__ void prep_kernel(const float* __restrict__ emb,  const float* __restrict__ W_ih,
                            const float* __restrict__ W_hh, const float* __restrict__ b_ih,
                            const float* __restrict__ b_hh, short* __restrict__ Apack) {
  int idx = blockIdx.x * 256 + threadIdx.x;       // total 13*2*64*8 = 13312
  if (idx >= 13 * 2 * 64 * 8) return;
  int j    = idx & 7;
  int lane = (idx >> 3) & 63;
  int kf   = (idx >> 9) & 1;
  int tid  = idx >> 10;                            // tile 0..12
  int m    = lane & 15;
  int q    = m >> 2, g = m & 3;
  int jh   = (tid < 10) ? (2 * ((tid >> 1) * 4 + q) + (tid & 1))
                        : (40 + (tid - 10) * 4 + q);
  int k    = kf * 32 + (lane >> 4) * 8 + j;
  float v = 0.0f;
  if (jh < HID) {
    int R = g * HID + jh;
    float scale = (g == 2) ? -2.885390082f : -1.442695041f;
    if (k < HID) {
      v = W_hh[R * HID + k] * scale;
    } else {
      int vo = k - HID;                            // vocab id 0..13
      float s = b_ih[R] + b_hh[R];
      for (int e = 0; e < EMB; ++e) s += emb[vo * EMB + e] * W_ih[R * EMB + e];
      v = s * scale;
    }
  }
  Apack[idx] = f2bf(v);
}

// ---------------------------------------------------------------------------
// Main: 256 wgs x 512 threads (8 waves), one wg owns 16 batch rows.
// R22 = R21 (700 us, best) + independent-rcp + fma-folds. (Resubmit —
// previous round was an infra failure, not a kernel failure.)
// R20 taught: trans issue is CHEAP. So the paired-rcp trick (shared
// rcp(d0*d1) + cross-muls) spends 3 VALU + a cross-cell join to save 1 rcp
// — inverted economics. Replace with per-cell rcp (+2 trans), deleting the
// scalar mul + 2 pk cross-muls and shortening the c->h chain ~2 levels.
// Fold hn = (1-H)*rv = fma(-H, rv, rv) (fats + singles). Net -6 VALU/fat,
// -1 VALU/single, +2 trans/fat. Watch: if this REGRESSES, the trans pipe
// is the new binding resource on SIMD1 (new info; revert).
// Lever ledger: setprio +67 | cvtpk +23 | pk-epilogue +12 | deep-pk +9 |
// window-widen -37 | stagger -24 | indep-MFMA -60 | sw-exp2 -300.
// ---------------------------------------------------------------------------
__global__ __launch_bounds__(512, 1) void lstm_kernel(
    const int* __restrict__ tokens, const short* __restrict__ Apack,
    const float* __restrict__ W1, const float* __restrict__ b1,
    const float* __restrict__ W2, const float* __restrict__ b2,
    float* __restrict__ out) {
  __shared__ __align__(16) unsigned char toku8[16 * TROW];   // 32832 B
  __shared__ __align__(16) short hbuf[2][16 * 64];           // 4096 B, swizzled
  __shared__ float hfin[16 * 52];
  __shared__ float mlp_hid[16 * 52];

  const int tid  = threadIdx.x;
  const int lane = tid & 63;
  const int wv   = tid >> 6;
  const int b0   = blockIdx.x * 16;
  const int bB   = lane & 15;          // batch col (B-frag & C col)
  const int jj   = lane >> 4;          // quad

  // wave roles: fat mask {0,1,2,5,7} = 0xA7, singles {3,4,6} = 0x58
  const bool two = (0xA7 >> wv) & 1;
  const int  fr  = __builtin_popcount(0xA7 & ((1 << wv) - 1));  // fat rank
  const int  sr  = __builtin_popcount(0x58 & ((1 << wv) - 1));  // single rank
  const int  p   = fr * 4 + jj;                  // fat: jh pair (2p, 2p+1)
  const int  jhS = 40 + sr * 4 + jj;             // single: jh (50,51 = pad)
  const bool sval = !two && (jhS < HID);

  // persistent A fragments
  const int t0 = two ? (fr * 2) : (10 + sr);
  bf16x8 Af00 = *(const bf16x8*)(Apack + ((t0 * 2 + 0) * 64 + lane) * 8);
  bf16x8 Af01 = *(const bf16x8*)(Apack + ((t0 * 2 + 1) * 64 + lane) * 8);
  bf16x8 Af10 = {}, Af11 = {};
  if (two) {
    Af10 = *(const bf16x8*)(Apack + (((t0 + 1) * 2 + 0) * 64 + lane) * 8);
    Af11 = *(const bf16x8*)(Apack + (((t0 + 1) * 2 + 1) * 64 + lane) * 8);
  }

  // one-hot duty: waves 3,4 -> 56 lanes each (8 batch rows x 7 words)
  const bool ohact = (wv == 3 || wv == 4) && (lane < 56);
  const int ohr   = (wv - 3) * 8 + lane / 7;    // batch row 0..15
  const int ohsub = lane % 7;                    // word covering vocab 2w,2w+1
  const int ohoct = (ohsub < 3) ? 6 : 7;
  const int ohinn = (ohsub < 3) ? (4 + 4 * ohsub) : (4 * (ohsub - 3));
  const int ohb   = ohr * 128 + 16 * ((ohoct + ohr) & 7) + ohinn;
  const int ohv0  = 2 * ohsub, ohv1 = 2 * ohsub + 1;

  // ---- stage tokens (int32 -> u8) and zero hbuf[0]
  for (int i = tid; i < 16 * 512; i += 512) {          // 8192 int4-groups
    int row = i >> 9, c4 = i & 511;
    int4 tv = *(const int4*)&tokens[(b0 + row) * SEQ + 4 * c4];
    unsigned pk = (tv.x & 0xFF) | ((tv.y & 0xFF) << 8) |
                  ((tv.z & 0xFF) << 16) | ((tv.w & 0xFF) << 24);
    *(unsigned*)&toku8[row * TROW + 4 * c4] = pk;
  }
  for (int i = tid; i < 1024; i += 512) hbuf[0][i] = 0;
  __syncthreads();

  // loop-invariant LDS byte offsets (XOR-swizzled 128 B rows)
  char* hb = (char*)hbuf;
  const int rb0   = bB * 128 + 16 * ((jj + bB) & 7);          // B octet jj
  const int rb1   = bB * 128 + 16 * (((jj + 4) + bB) & 7);    // B octet jj+4
  const int hwb32 = bB * 128 + 16 * (((p >> 2) + bB) & 7) + ((4 * p) & 15);
  const int hwb16 = bB * 128 + 16 * (((jhS >> 3) + bB) & 7) + 2 * (jhS & 7);
  const unsigned char* myrow = &toku8[bB * TROW];    // keep-mask tokens
  const unsigned char* ohtok = &toku8[ohr * TROW];   // one-hot tokens

  // one-hot for t=0
  if (ohact) {
    int tk = ohtok[0];
    unsigned wb = ((tk == ohv0) ? 0x3F80u : 0u) | ((tk == ohv1) ? 0x3F800000u : 0u);
    *(unsigned*)(hb + ohb) = wb;
  }

  f32x2 c01 = {0.f, 0.f}, h01 = {0.f, 0.f};   // fat: 2 cells; single uses [0]
  unsigned mp = 0;

  for (int t = 0; t < SEQ; t += 16) {
#pragma unroll
    for (int u = 0; u < 16; ++u) {
      const int T  = t + u;
      const int PB = (u & 1) * 2048, PN = PB ^ 2048;
      __syncthreads();   // hbuf[PB] ready; LDS-only -> lgkmcnt drain

      bf16x8 Bf0 = *(const bf16x8*)(hb + PB + rb0);
      bf16x8 Bf1 = *(const bf16x8*)(hb + PB + rb1);
      if ((u & 3) == 0) mp = *(const unsigned*)(myrow + T);   // tokens T..T+3

      const bool keep = (((mp >> (8 * (u & 3))) & 0xFF) != 0);

      if (two) {
        // ---- fat waves: prioritized MFMA + epilogue (R16 placement, prio1)
        __builtin_amdgcn_s_setprio(1);
        f32x4 acc0 = {0.f, 0.f, 0.f, 0.f};
        acc0 = __builtin_amdgcn_mfma_f32_16x16x32_bf16(Af00, Bf0, acc0, 0, 0, 0);
        acc0 = __builtin_amdgcn_mfma_f32_16x16x32_bf16(Af01, Bf1, acc0, 0, 0, 0);
        f32x4 acc1 = {0.f, 0.f, 0.f, 0.f};
        acc1 = __builtin_amdgcn_mfma_f32_16x16x32_bf16(Af10, Bf0, acc1, 0, 0, 0);
        acc1 = __builtin_amdgcn_mfma_f32_16x16x32_bf16(Af11, Bf1, acc1, 0, 0, 0);

        // paired fused-fraction cells, packed-f32, independent rcps
        f32x2 eA = {__builtin_amdgcn_exp2f(acc0[0]), __builtin_amdgcn_exp2f(acc1[0])};
        f32x2 eB = {__builtin_amdgcn_exp2f(acc0[1]), __builtin_amdgcn_exp2f(acc1[1])};
        f32x2 eC = {__builtin_amdgcn_exp2f(acc0[2]), __builtin_amdgcn_exp2f(acc1[2])};
        f32x2 eG = {__builtin_amdgcn_exp2f(acc0[3]), __builtin_amdgcn_exp2f(acc1[3])};
        const f32x2 one2 = {1.f, 1.f};
        f32x2 bb = one2 + eB;
        f32x2 cc = one2 + eC;
        f32x2 gg = one2 + eG;
        f32x2 P  = eA * cc + cc;          // (1+eA)*(1+eC)
        f32x2 t1 = bb - eC * bb;          // b1*(1-eC)
        f32x2 num = c01 * P + t1;
        f32x2 den = P * bb;
        f32x2 rd = {__builtin_amdgcn_rcpf(den[0]), __builtin_amdgcn_rcpf(den[1])};
        f32x2 cn  = num * rd;
        f32x2 clv = cn * -2.885390082f;          // pk-mul
        float cl0 = fminf(clv[0], 40.0f);
        float cl1 = fminf(clv[1], 40.0f);
        f32x2 H = {__builtin_amdgcn_exp2f(cl0), __builtin_amdgcn_exp2f(cl1)};
        f32x2 hd = gg * H + gg;           // g1*(1+H)
        f32x2 rv = {__builtin_amdgcn_rcpf(hd[0]), __builtin_amdgcn_rcpf(hd[1])};
        f32x2 hn = rv - H * rv;           // (1-H)/hd as one pk_fma
        c01[0] = keep ? cn[0] : c01[0];  h01[0] = keep ? hn[0] : h01[0];
        c01[1] = keep ? cn[1] : c01[1];  h01[1] = keep ? hn[1] : h01[1];
        *(unsigned*)(hb + PN + hwb32) = cvtpk(h01[0], h01[1]);
        __builtin_amdgcn_s_setprio(0);
      } else {
        // ---- singles: one-hot for T+1 FIRST (token-only dep, fills ds_read
        // latency), then MFMA + short epilogue
        if (ohact && T + 1 < SEQ) {
          int tk = ohtok[T + 1];
          unsigned wb = ((tk == ohv0) ? 0x3F80u : 0u) |
                        ((tk == ohv1) ? 0x3F800000u : 0u);
          *(unsigned*)(hb + PN + ohb) = wb;
        }

        f32x4 acc0 = {0.f, 0.f, 0.f, 0.f};
        acc0 = __builtin_amdgcn_mfma_f32_16x16x32_bf16(Af00, Bf0, acc0, 0, 0, 0);
        acc0 = __builtin_amdgcn_mfma_f32_16x16x32_bf16(Af01, Bf1, acc0, 0, 0, 0);

        // single fused-fraction cell: 5 exp2 + 2 rcp, fma-folded
        float eA = __builtin_amdgcn_exp2f(acc0[0]);
        float eB = __builtin_amdgcn_exp2f(acc0[1]);
        float eC = __builtin_amdgcn_exp2f(acc0[2]);
        float eG = __builtin_amdgcn_exp2f(acc0[3]);
        float bb1 = 1.f + eB, cc1 = 1.f + eC, g1 = 1.f + eG;
        float P   = __builtin_fmaf(eA, cc1, cc1);     // (1+eA)*(1+eC)
        float t1  = __builtin_fmaf(-eC, bb1, bb1);
        float num = __builtin_fmaf(c01[0], P, t1);
        float den = P * bb1;
        float cn  = num * __builtin_amdgcn_rcpf(den);
        float cl  = fminf(cn * -2.885390082f, 40.0f);
        float eH  = __builtin_amdgcn_exp2f(cl);
        float hd  = __builtin_fmaf(g1, eH, g1);       // g1*(1+H)
        float rv  = __builtin_amdgcn_rcpf(hd);
        float hn  = __builtin_fmaf(-eH, rv, rv);      // (1-eH)/hd as one fma
        c01[0] = keep ? cn : c01[0];
        h01[0] = keep ? hn : h01[0];
        if (sval) *(short*)(hb + PN + hwb16) = (short)cvtpk(h01[0], h01[0]);
      }
    }
  }

  // ---- final h -> MLP -> sigmoid
  if (two) {
    hfin[bB * 52 + 2 * p]     = h01[0];
    hfin[bB * 52 + 2 * p + 1] = h01[1];
  } else if (sval) {
    hfin[bB * 52 + jhS] = h01[0];
  }
  __syncthreads();
  for (int idx = tid; idx < 16 * 64; idx += 512) {
    int b = idx >> 6, m = idx & 63;
    if (m < HID) {
      float s = b1[m];
      for (int j2 = 0; j2 < HID; ++j2) s += hfin[b * 52 + j2] * W1[m * HID + j2];
      mlp_hid[b * 52 + m] = s;
    }
  }
  __syncthreads();
  if (tid < 16) {
    float s = b2[0];
    for (int m2 = 0; m2 < HID; ++m2) s += mlp_hid[tid * 52 + m2] * W2[m2];
    out[b0 + tid] = fsigm(s);
  }
}

extern "C" void kernel_launch(void* const* d_in, const int* in_sizes, int n_in,
                              void* d_out, int out_size, void* d_ws, size_t ws_size,
                              hipStream_t stream) {
  const int*   tokens = (const int*)  d_in[0];
  const float* emb    = (const float*)d_in[1];
  const float* W_ih   = (const float*)d_in[2];
  const float* W_hh   = (const float*)d_in[3];
  const float* b_ih   = (const float*)d_in[4];
  const float* b_hh   = (const float*)d_in[5];
  const float* W1     = (const float*)d_in[6];
  const float* b1     = (const float*)d_in[7];
  const float* W2     = (const float*)d_in[8];
  const float* b2     = (const float*)d_in[9];
  float* outp  = (float*)d_out;
  short* Apack = (short*)d_ws;                 // 13312 bf16 = 26.6 KB

  hipLaunchKernelGGL(prep_kernel, dim3(52), dim3(256), 0, stream,
                     emb, W_ih, W_hh, b_ih, b_hh, Apack);
  hipLaunchKernelGGL(lstm_kernel, dim3(BATCH / 16), dim3(512), 0, stream,
                     tokens, Apack, W1, b1, W2, b2, outp);
}